// Round 1
// baseline (718.255 us; speedup 1.0000x reference)
//
#include <hip/hip_runtime.h>
#include <math.h>

#define B_ 32
#define C_ 256
#define HW_ 3136      // 56*56
#define HW4_ 784      // HW/4 (float4 = 16B chunks)
#define G_ 32
#define EPS_ 1e-5f

#define GRID_ 1024    // 4 blocks/CU * 256 CU -> all co-resident (launch_bounds(256,4))
#define PPB_ 8        // planes per block = B_*C_/GRID_

// ws layout (floats):
//   [0 .. 8191]   pooled[b*C + c]
//   [8192 .. ]    cnt[32] (uint, per-image arrival counters, memset to 0 per launch)
#define WS_POOL 0
#define WS_CNT  (B_ * C_)

__global__ __launch_bounds__(256, 4) void fused_kernel(
    const float* __restrict__ x,
    const float* __restrict__ alpha_w, const float* __restrict__ alpha_b,
    const float* __restrict__ g_w, const float* __restrict__ g_b,
    const float* __restrict__ g_rm, const float* __restrict__ g_rv,
    const float* __restrict__ grp_w, const float* __restrict__ grp_b,
    const float* __restrict__ grp_rm, const float* __restrict__ grp_rv,
    float* __restrict__ ws, float* __restrict__ out) {
    const int tid  = threadIdx.x;
    const int lane = tid & 63, wv = tid >> 6;
    float* pooled = ws + WS_POOL;
    unsigned int* cnt = (unsigned int*)(ws + WS_CNT);

    __shared__ float red[4];
    __shared__ float bcast[2];   // sc, sh

    // ---- pool one (b,c) plane: mean over HW, then signal image counter ----
    auto pool_plane = [&](int p) {
        const float4* __restrict__ px = (const float4*)(x + (size_t)p * HW_);
        float s = 0.f;
        for (int i = tid; i < HW4_; i += 256) {
            float4 v = px[i];
            s += v.x + v.y + v.z + v.w;
        }
        #pragma unroll
        for (int off = 32; off; off >>= 1) s += __shfl_down(s, off);
        if (lane == 0) red[wv] = s;
        __syncthreads();
        if (tid == 0) {
            pooled[p] = (red[0] + red[1] + red[2] + red[3]) * (1.f / HW_);
            // release: pooled[p] store ordered before the arrival increment
            __hip_atomic_fetch_add(&cnt[p >> 8], 1u,
                                   __ATOMIC_RELEASE, __HIP_MEMORY_SCOPE_AGENT);
        }
        __syncthreads();   // red[] reuse safety
    };

    // ---- apply one (b,c) plane: wait image ready, alpha + param fold, stream ----
    auto apply_plane = [&](int p) {
        const int img = p >> 8, c = p & (C_ - 1);
        if (tid == 0) {
            // acquire spin: all 256 planes of this image pooled & visible
            while (__hip_atomic_load(&cnt[img], __ATOMIC_ACQUIRE,
                                     __HIP_MEMORY_SCOPE_AGENT) < (unsigned)C_) {
                __builtin_amdgcn_s_sleep(2);
            }
        }
        __syncthreads();

        // alpha[img] = sigmoid(dot(pooled[img,:], alpha_w) + alpha_b)
        float s = pooled[img * C_ + tid] * alpha_w[tid];
        #pragma unroll
        for (int off = 32; off; off >>= 1) s += __shfl_down(s, off);
        if (lane == 0) red[wv] = s;
        __syncthreads();

        // param fold for channel c (lanes 0..31 = groups), batch-independent
        if (tid < G_) {
            const int g = tid;
            float sg = grp_w[g * C_ + c] * rsqrtf(grp_rv[g * C_ + c] + EPS_);
            float sh = grp_b[g * C_ + c] - grp_rm[g * C_ + c] * sg;
            #pragma unroll
            for (int off = 16; off; off >>= 1) {
                sg += __shfl_down(sg, off);
                sh += __shfl_down(sh, off);
            }
            if (g == 0) {
                float a   = 1.f / (1.f + __expf(-(red[0] + red[1] + red[2] + red[3]
                                                  + alpha_b[0])));
                float ms  = sg * (1.f / G_);
                float msh = sh * (1.f / G_);
                float gsv = g_w[c] * rsqrtf(g_rv[c] + EPS_);
                float gsh = g_b[c] - g_rm[c] * gsv;
                bcast[0] = fmaf(a, ms  - gsv, gsv);   // (1-a)*gs + a*ms
                bcast[1] = fmaf(a, msh - gsh, gsh);
            }
        }
        __syncthreads();
        const float sc = bcast[0], sh = bcast[1];

        const float4* __restrict__ px = (const float4*)(x + (size_t)p * HW_);
        float4* __restrict__ po = (float4*)(out + (size_t)p * HW_);
        for (int i = tid; i < HW4_; i += 256) {
            float4 v = px[i];
            float4 r;
            r.x = fmaf(v.x, sc, sh);
            r.y = fmaf(v.y, sc, sh);
            r.z = fmaf(v.z, sc, sh);
            r.w = fmaf(v.w, sc, sh);
            __builtin_nontemporal_store(r.x, &po[i].x);
            __builtin_nontemporal_store(r.y, &po[i].y);
            __builtin_nontemporal_store(r.z, &po[i].z);
            __builtin_nontemporal_store(r.w, &po[i].w);
        }
        __syncthreads();   // red/bcast reuse safety
    };

    // software pipeline: pool batch t (pure read) overlaps apply batch t-1 (read+write)
    int prev = -1;
    for (int t = 0; t < PPB_; ++t) {
        const int p = t * GRID_ + blockIdx.x;
        pool_plane(p);
        if (prev >= 0) apply_plane(prev);
        prev = p;
    }
    apply_plane(prev);
}

extern "C" void kernel_launch(void* const* d_in, const int* in_sizes, int n_in,
                              void* d_out, int out_size, void* d_ws, size_t ws_size,
                              hipStream_t stream) {
    const float* x       = (const float*)d_in[0];
    const float* alpha_w = (const float*)d_in[2];
    const float* alpha_b = (const float*)d_in[3];
    const float* g_w     = (const float*)d_in[4];
    const float* g_b     = (const float*)d_in[5];
    const float* g_rm    = (const float*)d_in[6];
    const float* g_rv    = (const float*)d_in[7];
    const float* grp_w   = (const float*)d_in[8];
    const float* grp_b   = (const float*)d_in[9];
    const float* grp_rm  = (const float*)d_in[10];
    const float* grp_rv  = (const float*)d_in[11];
    float* out = (float*)d_out;
    float* ws  = (float*)d_ws;

    // zero the 32 per-image arrival counters (ws is poisoned by the harness)
    hipMemsetAsync((char*)d_ws + WS_CNT * sizeof(float), 0,
                   B_ * sizeof(unsigned int), stream);

    fused_kernel<<<GRID_, 256, 0, stream>>>(x, alpha_w, alpha_b,
                                            g_w, g_b, g_rm, g_rv,
                                            grp_w, grp_b, grp_rm, grp_rv,
                                            ws, out);
}

// Round 4
// 232.131 us; speedup vs baseline: 3.0942x; 3.0942x over previous
//
#include <hip/hip_runtime.h>
#include <math.h>

#define B_ 32
#define C_ 256
#define HW_ 3136      // 56*56
#define HW4_ 784      // HW/4 (float4 chunks); 784 = 3*256 + 16
#define G_ 32
#define EPS_ 1e-5f

#define GRID_ 1024    // 4 blocks/CU * 256 CU = exact guaranteed co-residency
#define PPB_ 8        // planes per block; block bid -> planes [bid*8, bid*8+8), one image

typedef float v4f __attribute__((ext_vector_type(4)));

// ws layout: per image img, one 128B line: ws32[img*32 + 0] = z (float bits),
//                                          ws32[img*32 + 1] = cnt (uint)
// memset to 0 per launch (4 KB).

__global__ __launch_bounds__(256, 4) void fused_kernel(
    const float* __restrict__ x,
    const float* __restrict__ alpha_w, const float* __restrict__ alpha_b,
    const float* __restrict__ g_w, const float* __restrict__ g_b,
    const float* __restrict__ g_rm, const float* __restrict__ g_rv,
    const float* __restrict__ grp_w, const float* __restrict__ grp_b,
    const float* __restrict__ grp_rm, const float* __restrict__ grp_rv,
    float* __restrict__ ws, float* __restrict__ out)
{
    const int bid = blockIdx.x, tid = threadIdx.x;
    const int lane = tid & 63, wv = tid >> 6;
    const int p0 = bid * PPB_;
    const int img = bid >> 5;
    const int c0 = p0 & (C_ - 1);
    const float4* __restrict__ xb = (const float4*)(x + (size_t)p0 * HW_);
    v4f* __restrict__ ob = (v4f*)(out + (size_t)p0 * HW_);

    float* z_p = ws + (size_t)img * 32;                 // float accumulator
    unsigned int* cnt_p = (unsigned int*)(z_p + 1);     // arrival counter (same line)

    __shared__ float red[4][PPB_];
    __shared__ float gs_sh[PPB_], gsh_sh[PPB_], dsc_sh[PPB_], dsh_sh[PPB_];
    __shared__ float a_sh;

    float4 v[PPB_][3];   // 96 VGPRs, live across the barrier
    float  s[PPB_];

    // ---- phase 1: load 24 float4/thread into registers, pool 8 planes ----
    #pragma unroll
    for (int t = 0; t < PPB_; ++t) {
        const int base = t * HW4_;
        v[t][0] = xb[base + tid];
        v[t][1] = xb[base + 256 + tid];
        v[t][2] = xb[base + 512 + tid];
        float st = v[t][0].x + v[t][0].y + v[t][0].z + v[t][0].w;
        st += v[t][1].x + v[t][1].y + v[t][1].z + v[t][1].w;
        st += v[t][2].x + v[t][2].y + v[t][2].z + v[t][2].w;
        if (tid < 16) {                    // tail (2% of plane): re-read from L3 later
            float4 w = xb[base + 768 + tid];
            st += w.x + w.y + w.z + w.w;
        }
        s[t] = st;
    }
    #pragma unroll
    for (int t = 0; t < PPB_; ++t) {
        float st = s[t];
        #pragma unroll
        for (int off = 32; off; off >>= 1) st += __shfl_down(st, off);
        if (lane == 0) red[wv][t] = st;
    }
    __syncthreads();

    // ---- arrival: one relaxed float-add + one release increment per block ----
    if (tid == 0) {
        float partial = 0.f;
        #pragma unroll
        for (int t = 0; t < PPB_; ++t) {
            float pooled_t = (red[0][t] + red[1][t] + red[2][t] + red[3][t])
                             * (1.f / HW_);
            partial += pooled_t * alpha_w[c0 + t];
        }
        __hip_atomic_fetch_add(z_p, partial,
                               __ATOMIC_RELAXED, __HIP_MEMORY_SCOPE_AGENT);
        __hip_atomic_fetch_add(cnt_p, 1u,
                               __ATOMIC_RELEASE, __HIP_MEMORY_SCOPE_AGENT);
    }

    // ---- batch-independent group-param fold (covers the wait) ----
    // thread (t_,g_) = (channel slot 0..7, group 0..31)
    {
        const int t_ = tid >> 5, g_ = tid & 31;
        const int c_ = c0 + t_;
        float sg  = grp_w[g_ * C_ + c_] * rsqrtf(grp_rv[g_ * C_ + c_] + EPS_);
        float shv = grp_b[g_ * C_ + c_] - grp_rm[g_ * C_ + c_] * sg;
        #pragma unroll
        for (int off = 16; off; off >>= 1) {   // 32-wide halves: lanes 0,32 hold sums
            sg  += __shfl_down(sg, off);
            shv += __shfl_down(shv, off);
        }
        if (g_ == 0) {
            float msv  = sg  * (1.f / G_);
            float mshv = shv * (1.f / G_);
            float gsv  = g_w[c_] * rsqrtf(g_rv[c_] + EPS_);
            float gshv = g_b[c_] - g_rm[c_] * gsv;
            gs_sh[t_]  = gsv;
            gsh_sh[t_] = gshv;
            dsc_sh[t_] = msv  - gsv;
            dsh_sh[t_] = mshv - gshv;
        }
    }

    // ---- image-local barrier: relaxed poll, single acquire fence ----
    if (tid == 0) {
        while (__hip_atomic_load(cnt_p, __ATOMIC_RELAXED,
                                 __HIP_MEMORY_SCOPE_AGENT) < 32u) {
            __builtin_amdgcn_s_sleep(16);
        }
        __builtin_amdgcn_fence(__ATOMIC_ACQUIRE, "agent");
        float zv = __hip_atomic_load(z_p, __ATOMIC_RELAXED,
                                     __HIP_MEMORY_SCOPE_AGENT);
        a_sh = 1.f / (1.f + __expf(-(zv + alpha_b[0])));
    }
    __syncthreads();
    const float a = a_sh;

    // ---- phase 2: apply from registers, stream out ----
    #pragma unroll
    for (int t = 0; t < PPB_; ++t) {
        const int base = t * HW4_;
        const float sc = fmaf(a, dsc_sh[t], gs_sh[t]);   // (1-a)*gs + a*ms
        const float sh = fmaf(a, dsh_sh[t], gsh_sh[t]);
        #pragma unroll
        for (int j = 0; j < 3; ++j) {
            v4f r;
            r.x = fmaf(v[t][j].x, sc, sh);
            r.y = fmaf(v[t][j].y, sc, sh);
            r.z = fmaf(v[t][j].z, sc, sh);
            r.w = fmaf(v[t][j].w, sc, sh);
            __builtin_nontemporal_store(r, &ob[base + j * 256 + tid]);
        }
        if (tid < 16) {
            float4 w = xb[base + 768 + tid];   // L3-hot tail re-read (2 MB grid-wide)
            v4f r;
            r.x = fmaf(w.x, sc, sh);
            r.y = fmaf(w.y, sc, sh);
            r.z = fmaf(w.z, sc, sh);
            r.w = fmaf(w.w, sc, sh);
            __builtin_nontemporal_store(r, &ob[base + 768 + tid]);
        }
    }
}

extern "C" void kernel_launch(void* const* d_in, const int* in_sizes, int n_in,
                              void* d_out, int out_size, void* d_ws, size_t ws_size,
                              hipStream_t stream) {
    const float* x       = (const float*)d_in[0];
    const float* alpha_w = (const float*)d_in[2];
    const float* alpha_b = (const float*)d_in[3];
    const float* g_w     = (const float*)d_in[4];
    const float* g_b     = (const float*)d_in[5];
    const float* g_rm    = (const float*)d_in[6];
    const float* g_rv    = (const float*)d_in[7];
    const float* grp_w   = (const float*)d_in[8];
    const float* grp_b   = (const float*)d_in[9];
    const float* grp_rm  = (const float*)d_in[10];
    const float* grp_rv  = (const float*)d_in[11];
    float* out = (float*)d_out;
    float* ws  = (float*)d_ws;

    // zero the 32 per-image {z, cnt} lines (ws is poisoned by the harness)
    hipMemsetAsync(ws, 0, B_ * 32 * sizeof(float), stream);

    fused_kernel<<<GRID_, 256, 0, stream>>>(x, alpha_w, alpha_b,
                                            g_w, g_b, g_rm, g_rv,
                                            grp_w, grp_b, grp_rm, grp_rv,
                                            ws, out);
}

// Round 5
// 222.888 us; speedup vs baseline: 3.2225x; 1.0415x over previous
//
#include <hip/hip_runtime.h>
#include <math.h>

#define B_ 32
#define C_ 256
#define HW_ 3136      // 56*56
#define HW4_ 784      // HW/4 (float4 chunks); 784 = 3*256 + 16
#define G_ 32
#define EPS_ 1e-5f

#define GRID_ 1024    // 4 blocks/CU * 256 CU = exact guaranteed co-residency
#define PPB_ 8        // planes per block; block bid -> planes [bid*8, bid*8+8), one image

typedef float v4f __attribute__((ext_vector_type(4)));

// ws layout: per image img, one 128B line: ws32[img*32 + 0] = z (float),
//                                          ws32[img*32 + 1] = cnt (uint)
// memset to 0 per launch (4 KB).

__global__ __launch_bounds__(256, 4) void fused_kernel(
    const float* __restrict__ x,
    const float* __restrict__ alpha_w, const float* __restrict__ alpha_b,
    const float* __restrict__ g_w, const float* __restrict__ g_b,
    const float* __restrict__ g_rm, const float* __restrict__ g_rv,
    const float* __restrict__ grp_w, const float* __restrict__ grp_b,
    const float* __restrict__ grp_rm, const float* __restrict__ grp_rv,
    float* __restrict__ ws, float* __restrict__ out)
{
    const int bid = blockIdx.x, tid = threadIdx.x;
    const int lane = tid & 63, wv = tid >> 6;
    const int p0 = bid * PPB_;
    const int img = bid >> 5;
    const int c0 = p0 & (C_ - 1);
    const v4f* __restrict__ xb = (const v4f*)(x + (size_t)p0 * HW_);
    v4f* __restrict__ ob = (v4f*)(out + (size_t)p0 * HW_);

    float* z_p = ws + (size_t)img * 32;                 // float accumulator
    unsigned int* cnt_p = (unsigned int*)(z_p + 1);     // arrival counter (same line)

    __shared__ float red[4][PPB_];
    __shared__ float gs_sh[PPB_], gsh_sh[PPB_], dsc_sh[PPB_], dsh_sh[PPB_];
    __shared__ float a_sh;

    v4f  v0[PPB_], v1[PPB_];   // 64 VGPRs of plane data, PINNED across the barrier
    float s[PPB_];

    // ---- phase 1: load, pool 8 planes; pin chunks 0,1 in registers ----
    #pragma unroll
    for (int t = 0; t < PPB_; ++t) {
        const int base = t * HW4_;
        v0[t] = xb[base + tid];
        v1[t] = xb[base + 256 + tid];
        v4f v2 = xb[base + 512 + tid];          // transient: summed now, re-read (L3) later
        float st = v0[t].x + v0[t].y + v0[t].z + v0[t].w;
        st += v1[t].x + v1[t].y + v1[t].z + v1[t].w;
        st += v2.x + v2.y + v2.z + v2.w;
        if (tid < 16) {                          // tail (2%): re-read from L2/L3 later
            v4f w = xb[base + 768 + tid];
            st += w.x + w.y + w.z + w.w;
        }
        s[t] = st;
        // forbid rematerialization: compiler must hold v0/v1 in VGPRs from here on
        asm volatile("" : "+v"(v0[t]), "+v"(v1[t]));
    }
    #pragma unroll
    for (int t = 0; t < PPB_; ++t) {
        float st = s[t];
        #pragma unroll
        for (int off = 32; off; off >>= 1) st += __shfl_down(st, off);
        if (lane == 0) red[wv][t] = st;
    }
    __syncthreads();

    // ---- arrival: one relaxed float-add + one release increment per block ----
    if (tid == 0) {
        float partial = 0.f;
        #pragma unroll
        for (int t = 0; t < PPB_; ++t) {
            float pooled_t = (red[0][t] + red[1][t] + red[2][t] + red[3][t])
                             * (1.f / HW_);
            partial += pooled_t * alpha_w[c0 + t];
        }
        __hip_atomic_fetch_add(z_p, partial,
                               __ATOMIC_RELAXED, __HIP_MEMORY_SCOPE_AGENT);
        __hip_atomic_fetch_add(cnt_p, 1u,
                               __ATOMIC_RELEASE, __HIP_MEMORY_SCOPE_AGENT);
    }

    // ---- batch-independent group-param fold (covers the wait) ----
    {
        const int t_ = tid >> 5, g_ = tid & 31;
        const int c_ = c0 + t_;
        float sg  = grp_w[g_ * C_ + c_] * rsqrtf(grp_rv[g_ * C_ + c_] + EPS_);
        float shv = grp_b[g_ * C_ + c_] - grp_rm[g_ * C_ + c_] * sg;
        #pragma unroll
        for (int off = 16; off; off >>= 1) {   // 32-wide halves: lanes 0,32 hold sums
            sg  += __shfl_down(sg, off);
            shv += __shfl_down(shv, off);
        }
        if (g_ == 0) {
            float msv  = sg  * (1.f / G_);
            float mshv = shv * (1.f / G_);
            float gsv  = g_w[c_] * rsqrtf(g_rv[c_] + EPS_);
            float gshv = g_b[c_] - g_rm[c_] * gsv;
            gs_sh[t_]  = gsv;
            gsh_sh[t_] = gshv;
            dsc_sh[t_] = msv  - gsv;
            dsh_sh[t_] = mshv - gshv;
        }
    }

    // ---- image-local barrier: relaxed poll, single acquire fence ----
    if (tid == 0) {
        while (__hip_atomic_load(cnt_p, __ATOMIC_RELAXED,
                                 __HIP_MEMORY_SCOPE_AGENT) < 32u) {
            __builtin_amdgcn_s_sleep(4);
        }
        __builtin_amdgcn_fence(__ATOMIC_ACQUIRE, "agent");
        float zv = __hip_atomic_load(z_p, __ATOMIC_RELAXED,
                                     __HIP_MEMORY_SCOPE_AGENT);
        a_sh = 1.f / (1.f + __expf(-(zv + alpha_b[0])));
    }
    __syncthreads();
    const float a = a_sh;

    // ---- phase 2: chunks 0,1 from registers; chunk 2 + tail re-read (L3-hot) ----
    #pragma unroll
    for (int t = 0; t < PPB_; ++t) {
        const int base = t * HW4_;
        const float sc = fmaf(a, dsc_sh[t], gs_sh[t]);   // (1-a)*gs + a*ms
        const float sh = fmaf(a, dsh_sh[t], gsh_sh[t]);

        v4f v2 = xb[base + 512 + tid];        // issue re-load first: hides under stores
        v4f w;
        if (tid < 16) w = xb[base + 768 + tid];

        v4f r0, r1;
        r0.x = fmaf(v0[t].x, sc, sh); r0.y = fmaf(v0[t].y, sc, sh);
        r0.z = fmaf(v0[t].z, sc, sh); r0.w = fmaf(v0[t].w, sc, sh);
        __builtin_nontemporal_store(r0, &ob[base + tid]);
        r1.x = fmaf(v1[t].x, sc, sh); r1.y = fmaf(v1[t].y, sc, sh);
        r1.z = fmaf(v1[t].z, sc, sh); r1.w = fmaf(v1[t].w, sc, sh);
        __builtin_nontemporal_store(r1, &ob[base + 256 + tid]);

        v4f r2;
        r2.x = fmaf(v2.x, sc, sh); r2.y = fmaf(v2.y, sc, sh);
        r2.z = fmaf(v2.z, sc, sh); r2.w = fmaf(v2.w, sc, sh);
        __builtin_nontemporal_store(r2, &ob[base + 512 + tid]);

        if (tid < 16) {
            v4f rw;
            rw.x = fmaf(w.x, sc, sh); rw.y = fmaf(w.y, sc, sh);
            rw.z = fmaf(w.z, sc, sh); rw.w = fmaf(w.w, sc, sh);
            __builtin_nontemporal_store(rw, &ob[base + 768 + tid]);
        }
    }
}

extern "C" void kernel_launch(void* const* d_in, const int* in_sizes, int n_in,
                              void* d_out, int out_size, void* d_ws, size_t ws_size,
                              hipStream_t stream) {
    const float* x       = (const float*)d_in[0];
    const float* alpha_w = (const float*)d_in[2];
    const float* alpha_b = (const float*)d_in[3];
    const float* g_w     = (const float*)d_in[4];
    const float* g_b     = (const float*)d_in[5];
    const float* g_rm    = (const float*)d_in[6];
    const float* g_rv    = (const float*)d_in[7];
    const float* grp_w   = (const float*)d_in[8];
    const float* grp_b   = (const float*)d_in[9];
    const float* grp_rm  = (const float*)d_in[10];
    const float* grp_rv  = (const float*)d_in[11];
    float* out = (float*)d_out;
    float* ws  = (float*)d_ws;

    // zero the 32 per-image {z, cnt} lines (ws is poisoned by the harness)
    hipMemsetAsync(ws, 0, B_ * 32 * sizeof(float), stream);

    fused_kernel<<<GRID_, 256, 0, stream>>>(x, alpha_w, alpha_b,
                                            g_w, g_b, g_rm, g_rv,
                                            grp_w, grp_b, grp_rm, grp_rv,
                                            ws, out);
}